// Round 10
// baseline (382.780 us; speedup 1.0000x reference)
//
#include <hip/hip_runtime.h>

// Problem constants
#define BSZ 16
#define NN  128
#define HH  256
#define LLG 9
#define FFE 48   // edge feature dim (padded to 64 for MFMA K)

typedef float        f32x4 __attribute__((ext_vector_type(4)));
typedef _Float16     f16x8 __attribute__((ext_vector_type(8)));
typedef unsigned int u32x4 __attribute__((ext_vector_type(4)));

static __device__ __forceinline__ unsigned short f2h_bits(float x) {
    _Float16 h = (_Float16)x;   // RNE
    return __builtin_bit_cast(unsigned short, h);
}

static __device__ __forceinline__ float fast_silu(float x) {
    float e = __builtin_amdgcn_exp2f(x * -1.44269504088896341f);
    return x * __builtin_amdgcn_rcpf(1.0f + e);
}

// ---------------------------------------------------------------------------
// Kernel 1: weight transpose + f32->f16 convert.  (proven)
//   WeT[h][f]  (256 x 64, f>=48 zero-padded)  from W1 rows 521..568
//   W2T[ho][k] (256 x 256)                    from W2[k][ho]
// ---------------------------------------------------------------------------
__global__ __launch_bounds__(256) void pre_w(
    const float* __restrict__ W1, const float* __restrict__ W2,
    unsigned short* __restrict__ W2T, unsigned short* __restrict__ WeT)
{
    int tid = blockIdx.x * 256 + threadIdx.x;   // grid 256 -> 65536 threads
    {
        int ho = tid >> 8, k = tid & 255;
        W2T[(ho << 8) + k] = f2h_bits(W2[(k << 8) + ho]);  // coalesced write
    }
    if (tid < 256 * 64) {
        int h = tid >> 6, f = tid & 63;
        WeT[(h << 6) + f] = (f < FFE) ? f2h_bits(W1[(521 + f) * HH + h])
                                      : (unsigned short)0;
    }
}

// ---------------------------------------------------------------------------
// Kernel 2: pj[b,r,h] = node@Wj ; base[b,r,h] = node@Wi + graph@Wg + b1 (proven)
// ---------------------------------------------------------------------------
__global__ __launch_bounds__(256) void pre_pjbase(
    const float* __restrict__ node, const float* __restrict__ graph,
    const float* __restrict__ W1, const float* __restrict__ b1,
    float* __restrict__ pj, float* __restrict__ base)
{
    __shared__ float nrow[4][HH];
    __shared__ float gsh[LLG];
    const int blk = blockIdx.x;
    const int b = blk >> 5;             // 32 row-groups of 4 per batch
    const int r0 = (blk & 31) << 2;
    const int h = threadIdx.x;

    for (int t = h; t < 4 * HH; t += 256) {
        int r = t >> 8, k = t & 255;
        nrow[r][k] = node[(((size_t)b * NN) + r0 + r) * HH + k];
    }
    if (h < LLG) gsh[h] = graph[b * LLG + h];
    __syncthreads();

    float accj[4] = {0,0,0,0};
    float acci[4] = {0,0,0,0};
    for (int k = 0; k < HH; ++k) {
        float wj = W1[k * HH + h];
        float wi = W1[(k + HH) * HH + h];
        #pragma unroll
        for (int r = 0; r < 4; ++r) {
            float nv = nrow[r][k];
            accj[r] = fmaf(nv, wj, accj[r]);
            acci[r] = fmaf(nv, wi, acci[r]);
        }
    }
    float accg = b1[h];
    #pragma unroll
    for (int l = 0; l < LLG; ++l)
        accg = fmaf(gsh[l], W1[(2 * HH + l) * HH + h], accg);

    #pragma unroll
    for (int r = 0; r < 4; ++r) {
        size_t off = (((size_t)b * NN) + r0 + r) * HH + h;
        pj[off]   = accj[r];
        base[off] = acci[r] + accg;
    }
}

// ---------------------------------------------------------------------------
// Kernel 3: fused main — j-sliced, wave-private, barrier-free pipeline.
// Wave w owns j in [16w, 16w+16). Per wave:
//   GEMM1: D1[h(256) x j(16)] : A = WeT rows h (16 tiles), B = edge rows j
//          loaded DIRECT from global (no staging phase, no barrier).
//   epi1:  z1 = D1 + base[i][h] + pj[j][h]; silu; pack f16 pairs;
//          ds_write_b64 into the wave's PRIVATE 8 KB LDS strip (XOR-swizzled).
//   GEMM2: A = strip (row j = lane c, k = h: lane-local!), B = W2T rows ho.
//          128 MFMA, acc2[16].
//   epi2:  silu + within-lane j-sum + quad butterfly -> partial per ho.
// Cross-wave: ONE __syncthreads + 8-way sum of 8x256 partials.
// Rationale: R5-R9 showed VALU/MFMA/LDS phases serialize chip-wide behind
// block barriers. Free-running waves overlap the pipes instead.
// ---------------------------------------------------------------------------
__global__ __launch_bounds__(512, 4) void fused_msg(
    const float* __restrict__ edge, const float* __restrict__ pj,
    const float* __restrict__ base, const unsigned short* __restrict__ W2T,
    const unsigned short* __restrict__ WeT, const float* __restrict__ b2,
    float* __restrict__ out)
{
    __shared__ __align__(128) unsigned char lds[8 * 8192 + 8192];   // 72 KB
    const int tid  = threadIdx.x;
    const int w    = tid >> 6;         // wave 0..7 (owns j-slice)
    const int lane = tid & 63;
    const int q    = lane >> 4;        // quad 0..3
    const int c    = lane & 15;
    const int bi   = blockIdx.x;       // b*128 + i
    const int b    = bi >> 7;

    unsigned char* h1w = lds + (w << 13);          // wave-private 8 KB strip
    float* wred = (float*)(lds + 65536);           // 8 x 256 f32 reduce buffer

    const int jrow = (w << 4) + c;                 // this lane's j
    const float* eb = edge + (size_t)bi * (NN * FFE) + jrow * FFE;
    const unsigned ck = (unsigned)(c & 7) << 4;    // lane-constant XOR key

    // ---- B-fragments of GEMM1: edge[j=jrow][f] direct from global ----
    // lane (c,q) holds B[col=c][k=f=q*8+e]; kk=0 -> f 0..31, kk=1 -> f 32..63
    f16x8 bf0, bf1;
    {
        const f32x4 x0 = *reinterpret_cast<const f32x4*>(eb + (q << 3));
        const f32x4 x1 = *reinterpret_cast<const f32x4*>(eb + (q << 3) + 4);
        u32x4 u;
        u[0] = __builtin_bit_cast(unsigned int, __builtin_amdgcn_cvt_pkrtz(x0[0], x0[1]));
        u[1] = __builtin_bit_cast(unsigned int, __builtin_amdgcn_cvt_pkrtz(x0[2], x0[3]));
        u[2] = __builtin_bit_cast(unsigned int, __builtin_amdgcn_cvt_pkrtz(x1[0], x1[1]));
        u[3] = __builtin_bit_cast(unsigned int, __builtin_amdgcn_cvt_pkrtz(x1[2], x1[3]));
        bf0 = __builtin_bit_cast(f16x8, u);
    }
    if (q < 2) {   // f 32..47 real, f 48..63 are the zero pad
        const f32x4 x0 = *reinterpret_cast<const f32x4*>(eb + 32 + (q << 3));
        const f32x4 x1 = *reinterpret_cast<const f32x4*>(eb + 36 + (q << 3));
        u32x4 u;
        u[0] = __builtin_bit_cast(unsigned int, __builtin_amdgcn_cvt_pkrtz(x0[0], x0[1]));
        u[1] = __builtin_bit_cast(unsigned int, __builtin_amdgcn_cvt_pkrtz(x0[2], x0[3]));
        u[2] = __builtin_bit_cast(unsigned int, __builtin_amdgcn_cvt_pkrtz(x1[0], x1[1]));
        u[3] = __builtin_bit_cast(unsigned int, __builtin_amdgcn_cvt_pkrtz(x1[2], x1[3]));
        bf1 = __builtin_bit_cast(f16x8, u);
    } else {
        u32x4 z = {0u, 0u, 0u, 0u};
        bf1 = __builtin_bit_cast(f16x8, z);
    }

    // ---- GEMM1: 16 h-tiles x 2 K-chunks ----
    f32x4 acc1[16];
    #pragma unroll
    for (int t = 0; t < 16; ++t) acc1[t] = f32x4{0.f, 0.f, 0.f, 0.f};

    #pragma unroll
    for (int t = 0; t < 16; ++t) {
        const f16x8 af = *reinterpret_cast<const f16x8*>(
            WeT + (((t << 4) + c) << 6) + (q << 3));
        acc1[t] = __builtin_amdgcn_mfma_f32_16x16x32_f16(af, bf0, acc1[t], 0, 0, 0);
    }
    #pragma unroll
    for (int t = 0; t < 16; ++t) {
        const f16x8 af = *reinterpret_cast<const f16x8*>(
            WeT + (((t << 4) + c) << 6) + 32 + (q << 3));
        acc1[t] = __builtin_amdgcn_mfma_f32_16x16x32_f16(af, bf1, acc1[t], 0, 0, 0);
    }

    // ---- epi1: z1 -> silu -> f16 pairs -> wave-private strip ----
    // lane (c,q), tile t holds D1 rows h = t*16+q*4+r, col j = jrow.
    // strip layout: byte = c*512 + ((h*2) ^ ck); b64 covers h-pairs.
    const float* bbp = base + ((size_t)bi << 8) + (q << 2);
    const float* pjp = pj + (((size_t)b << 7) + jrow) * HH + (q << 2);
    #pragma unroll
    for (int t = 0; t < 16; ++t) {
        const f32x4 bb = *reinterpret_cast<const f32x4*>(bbp + (t << 4));
        const f32x4 pv = *reinterpret_cast<const f32x4*>(pjp + (t << 4));
        float s0 = fast_silu(acc1[t][0] + bb[0] + pv[0]);
        float s1 = fast_silu(acc1[t][1] + bb[1] + pv[1]);
        float s2 = fast_silu(acc1[t][2] + bb[2] + pv[2]);
        float s3 = fast_silu(acc1[t][3] + bb[3] + pv[3]);
        unsigned int lo = __builtin_bit_cast(unsigned int,
                            __builtin_amdgcn_cvt_pkrtz(s0, s1));
        unsigned int hi = __builtin_bit_cast(unsigned int,
                            __builtin_amdgcn_cvt_pkrtz(s2, s3));
        const unsigned off = (unsigned)(c << 9) +
            (((unsigned)((t << 5) + (q << 3))) ^ ck);
        *reinterpret_cast<uint2*>(&h1w[off]) = make_uint2(lo, hi);
    }
    // (compiler inserts lgkmcnt before the strip reads below; same-wave only)

    // ---- GEMM2: A = strip rows j (lane-local), B = W2T rows ho ----
    f32x4 acc2[16];
    #pragma unroll
    for (int n = 0; n < 16; ++n) acc2[n] = f32x4{0.f, 0.f, 0.f, 0.f};

    #pragma unroll
    for (int kc = 0; kc < 8; ++kc) {
        const unsigned roff = (unsigned)(c << 9) +
            (((unsigned)((kc << 6) + (q << 4))) ^ ck);
        const f16x8 pa = *reinterpret_cast<const f16x8*>(&h1w[roff]);
        #pragma unroll
        for (int n = 0; n < 16; ++n) {
            const f16x8 bw = *reinterpret_cast<const f16x8*>(
                W2T + (((n << 4) + c) << 8) + (kc << 5) + (q << 3));
            acc2[n] = __builtin_amdgcn_mfma_f32_16x16x32_f16(pa, bw, acc2[n], 0, 0, 0);
        }
    }

    // ---- epi2: silu + within-wave j-sum -> partial per ho ----
    #pragma unroll
    for (int n = 0; n < 16; ++n) {
        const float b2v = b2[(n << 4) + c];
        float t = fast_silu(acc2[n][0] + b2v) + fast_silu(acc2[n][1] + b2v)
                + fast_silu(acc2[n][2] + b2v) + fast_silu(acc2[n][3] + b2v);
        t += __shfl_xor(t, 16);
        t += __shfl_xor(t, 32);
        if (q == 0) wred[(w << 8) + (n << 4) + c] = t;
    }
    __syncthreads();   // the only block barrier

    // ---- cross-wave 8-way sum, scale, store ----
    if (tid < 256) {
        float acc = 0.f;
        #pragma unroll
        for (int wv = 0; wv < 8; ++wv) acc += wred[(wv << 8) + tid];
        out[((size_t)bi << 8) + tid] = acc * 0.0078125f;   // /128
    }
}

// ---------------------------------------------------------------------------
extern "C" void kernel_launch(void* const* d_in, const int* in_sizes, int n_in,
                              void* d_out, int out_size, void* d_ws, size_t ws_size,
                              hipStream_t stream)
{
    const float* node  = (const float*)d_in[0];
    const float* edge  = (const float*)d_in[1];
    const float* graph = (const float*)d_in[2];
    const float* W1    = (const float*)d_in[3];
    const float* b1    = (const float*)d_in[4];
    const float* W2    = (const float*)d_in[5];
    const float* b2    = (const float*)d_in[6];
    float* out = (float*)d_out;

    char* ws = (char*)d_ws;
    unsigned short* W2T = (unsigned short*)ws;              // 131072 B
    unsigned short* WeT = (unsigned short*)(ws + 131072);   //  32768 B
    float* pj   = (float*)(ws + 163840);                    // 2 MB
    float* base = (float*)(ws + 163840 + 2097152);          // 2 MB

    pre_w     <<<256, 256, 0, stream>>>(W1, W2, W2T, WeT);
    pre_pjbase<<<512, 256, 0, stream>>>(node, graph, W1, b1, pj, base);
    fused_msg <<<BSZ * NN, 512, 0, stream>>>(edge, pj, base, W2T, WeT, b2, out);
}

// Round 11
// 113.192 us; speedup vs baseline: 3.3817x; 3.3817x over previous
//
#include <hip/hip_runtime.h>

// Problem constants
#define BSZ 16
#define NN  128
#define HH  256
#define LLG 9
#define FFE 48   // edge feature dim (padded to 64 for MFMA K)

typedef float        f32x4 __attribute__((ext_vector_type(4)));
typedef _Float16     f16x8 __attribute__((ext_vector_type(8)));
typedef unsigned int u32x4 __attribute__((ext_vector_type(4)));

static __device__ __forceinline__ unsigned short f2h_bits(float x) {
    _Float16 h = (_Float16)x;   // RNE
    return __builtin_bit_cast(unsigned short, h);
}

static __device__ __forceinline__ float fast_silu(float x) {
    float e = __builtin_amdgcn_exp2f(x * -1.44269504088896341f);
    return x * __builtin_amdgcn_rcpf(1.0f + e);
}

// ---------------------------------------------------------------------------
// Kernel 1: weight transpose + f32->f16 convert.  (proven)
//   WeT[h][f]  (256 x 64, f>=48 zero-padded)  from W1 rows 521..568
//   W2T[ho][k] (256 x 256)                    from W2[k][ho]
// ---------------------------------------------------------------------------
__global__ __launch_bounds__(256) void pre_w(
    const float* __restrict__ W1, const float* __restrict__ W2,
    unsigned short* __restrict__ W2T, unsigned short* __restrict__ WeT)
{
    int tid = blockIdx.x * 256 + threadIdx.x;   // grid 256 -> 65536 threads
    {
        int ho = tid >> 8, k = tid & 255;
        W2T[(ho << 8) + k] = f2h_bits(W2[(k << 8) + ho]);  // coalesced write
    }
    if (tid < 256 * 64) {
        int h = tid >> 6, f = tid & 63;
        WeT[(h << 6) + f] = (f < FFE) ? f2h_bits(W1[(521 + f) * HH + h])
                                      : (unsigned short)0;
    }
}

// ---------------------------------------------------------------------------
// Kernel 2: pj/base precompute — R1's 8-rows-per-block version (256 blocks):
// halves the W1 re-stream vs the 512-block variant (134 MB vs 268 MB of L2).
// ---------------------------------------------------------------------------
__global__ __launch_bounds__(256) void pre_pjbase(
    const float* __restrict__ node, const float* __restrict__ graph,
    const float* __restrict__ W1, const float* __restrict__ b1,
    float* __restrict__ pj, float* __restrict__ base)
{
    __shared__ float nrow[8][HH];
    __shared__ float gsh[LLG];
    const int blk = blockIdx.x;
    const int b = blk >> 4;             // 16 row-groups of 8 per batch
    const int r0 = (blk & 15) << 3;
    const int h = threadIdx.x;

    for (int t = h; t < 8 * HH; t += 256) {
        int r = t >> 8, k = t & 255;
        nrow[r][k] = node[(((size_t)b * NN) + r0 + r) * HH + k];
    }
    if (h < LLG) gsh[h] = graph[b * LLG + h];
    __syncthreads();

    float accj[8] = {0,0,0,0,0,0,0,0};
    float acci[8] = {0,0,0,0,0,0,0,0};
    for (int k = 0; k < HH; ++k) {
        float wj = W1[k * HH + h];
        float wi = W1[(k + HH) * HH + h];
        #pragma unroll
        for (int r = 0; r < 8; ++r) {
            float nv = nrow[r][k];
            accj[r] = fmaf(nv, wj, accj[r]);
            acci[r] = fmaf(nv, wi, acci[r]);
        }
    }
    float accg = b1[h];
    #pragma unroll
    for (int l = 0; l < LLG; ++l)
        accg = fmaf(gsh[l], W1[(2 * HH + l) * HH + h], accg);

    #pragma unroll
    for (int r = 0; r < 8; ++r) {
        size_t off = (((size_t)b * NN) + r0 + r) * HH + h;
        pj[off]   = accj[r];
        base[off] = acci[r] + accg;
    }
}

// ---------------------------------------------------------------------------
// Kernel 3: fused main — round-5 structure VERBATIM (best measured: 92 us),
// plus T1 XCD-chunked block swizzle: consecutive bi (same batch -> same
// 524 KB pj/base working set) land on the SAME XCD's L2 instead of
// round-robining across all 8 (which needs 4.2 MB residency per L2).
// ---------------------------------------------------------------------------
__global__ __launch_bounds__(512, 4) void fused_msg(
    const float* __restrict__ edge, const float* __restrict__ pj,
    const float* __restrict__ base, const unsigned short* __restrict__ W2T,
    const unsigned short* __restrict__ WeT, const float* __restrict__ b2,
    float* __restrict__ out)
{
    __shared__ unsigned char h1s[NN * HH * 2];   // 64 KB: h1[j][h] f16, swizzled
    __shared__ unsigned char efs[NN * 64 * 2];   // 16 KB: edge[j][f] f16, padded+swizzled
    const int tid  = threadIdx.x;
    const int w    = tid >> 6;         // wave 0..7
    const int lane = tid & 63;
    const int q    = lane >> 4;        // quad 0..3
    const int c    = lane & 15;
    // T1: XCD-chunked swizzle (2048 blocks, 8 XCDs, 2048%8==0 -> bijective)
    const int g    = blockIdx.x;
    const int bi   = ((g & 7) << 8) + (g >> 3);   // b*128 + i
    const int b    = bi >> 7;

    const float* eb = edge + (size_t)bi * (NN * FFE);

    // ---- stage edge block -> f16 LDS, row-padded to 64 f16, XOR-swizzled ----
    #pragma unroll
    for (int p = 0; p < 3; ++p) {
        const int e4 = p * 512 + tid;            // float4 index, < 1536
        const int j  = e4 / 12;                  // 12 float4 per 48-float row
        const int f4 = e4 - j * 12;              // 0..11
        const f32x4 x = *reinterpret_cast<const f32x4*>(eb + (e4 << 2));
        unsigned int lo = __builtin_bit_cast(unsigned int,
                            __builtin_amdgcn_cvt_pkrtz(x[0], x[1]));
        unsigned int hi = __builtin_bit_cast(unsigned int,
                            __builtin_amdgcn_cvt_pkrtz(x[2], x[3]));
        const unsigned int off = (unsigned)(j << 7) +
            (((unsigned)(f4 << 3)) ^ ((unsigned)(j & 7) << 4));
        *reinterpret_cast<uint2*>(&efs[off]) = make_uint2(lo, hi);
    }
    {   // zero-fill padded f in [48,64)
        const int j = tid >> 2, gg = tid & 3;
        const unsigned int off = (unsigned)(j << 7) +
            (((unsigned)(96 + (gg << 3))) ^ ((unsigned)(j & 7) << 4));
        *reinterpret_cast<uint2*>(&efs[off]) = make_uint2(0u, 0u);
    }
    __syncthreads();

    // ------------------ GEMM1: D1[h(32), j(128)] ------------------
    f32x4 acc1[2][8];
    #pragma unroll
    for (int mt = 0; mt < 2; ++mt)
        #pragma unroll
        for (int nt = 0; nt < 8; ++nt) acc1[mt][nt] = f32x4{0.f, 0.f, 0.f, 0.f};

    #pragma unroll
    for (int kk = 0; kk < 2; ++kk) {
        const int koff = (kk << 5) + (q << 3);   // f16-units f offset
        const int fb   = koff << 1;              // byte offset in efs row
        f16x8 af[2];
        #pragma unroll
        for (int mt = 0; mt < 2; ++mt) {
            const int row = (w << 5) + (mt << 4) + c;       // h
            af[mt] = *reinterpret_cast<const f16x8*>(WeT + (row << 6) + koff);
        }
        #pragma unroll
        for (int nt = 0; nt < 8; ++nt) {
            const int j = (nt << 4) + c;
            const f16x8 bf = *reinterpret_cast<const f16x8*>(
                &efs[(unsigned)(j << 7) +
                     (((unsigned)fb) ^ ((unsigned)(j & 7) << 4))]);
            #pragma unroll
            for (int mt = 0; mt < 2; ++mt)
                acc1[mt][nt] = __builtin_amdgcn_mfma_f32_16x16x32_f16(
                    af[mt], bf, acc1[mt][nt], 0, 0, 0);
        }
    }

    // epilogue 1: z1 -> silu -> f16 -> h1s (swizzle: byte ^= (j&7)<<4)
    #pragma unroll
    for (int mt = 0; mt < 2; ++mt) {
        const int h0 = (w << 5) + (mt << 4) + (q << 2);
        const f32x4 bb = *reinterpret_cast<const f32x4*>(
            base + ((size_t)bi << 8) + h0);
        #pragma unroll
        for (int nt = 0; nt < 8; ++nt) {
            const int jc = (nt << 4) + c;
            const f32x4 pjv = *reinterpret_cast<const f32x4*>(
                pj + (((size_t)b << 7) + jc) * HH + h0);
            float s0 = fast_silu(acc1[mt][nt][0] + bb[0] + pjv[0]);
            float s1 = fast_silu(acc1[mt][nt][1] + bb[1] + pjv[1]);
            float s2 = fast_silu(acc1[mt][nt][2] + bb[2] + pjv[2]);
            float s3 = fast_silu(acc1[mt][nt][3] + bb[3] + pjv[3]);
            unsigned int lo = __builtin_bit_cast(unsigned int,
                                __builtin_amdgcn_cvt_pkrtz(s0, s1));
            unsigned int hi = __builtin_bit_cast(unsigned int,
                                __builtin_amdgcn_cvt_pkrtz(s2, s3));
            const unsigned int off = (unsigned)(jc << 9) +
                (((unsigned)(h0 << 1)) ^ ((unsigned)(jc & 7) << 4));
            *reinterpret_cast<uint2*>(&h1s[off]) = make_uint2(lo, hi);
        }
    }
    __syncthreads();

    // ------------------ GEMM2: D2[jc(128), ho(32)] ------------------
    f32x4 acc2[8][2];
    #pragma unroll
    for (int mt = 0; mt < 8; ++mt)
        #pragma unroll
        for (int nt = 0; nt < 2; ++nt) acc2[mt][nt] = f32x4{0.f, 0.f, 0.f, 0.f};

    #pragma unroll 2
    for (int kk = 0; kk < 8; ++kk) {
        const int kb = (kk << 6) + (q << 4);     // byte offset of k-slice
        f16x8 bw[2];
        #pragma unroll
        for (int nt = 0; nt < 2; ++nt) {
            const int ho = (w << 5) + (nt << 4) + c;
            bw[nt] = *reinterpret_cast<const f16x8*>(
                W2T + (ho << 8) + (kk << 5) + (q << 3));
        }
        #pragma unroll
        for (int gg = 0; gg < 2; ++gg) {
            f16x8 a2[4];
            #pragma unroll
            for (int m = 0; m < 4; ++m) {
                const int jc = ((gg << 2) + m) * 16 + c;
                const unsigned int off = (unsigned)(jc << 9) +
                    (((unsigned)kb) ^ ((unsigned)(jc & 7) << 4));
                a2[m] = *reinterpret_cast<const f16x8*>(&h1s[off]);
            }
            #pragma unroll
            for (int m = 0; m < 4; ++m)
                #pragma unroll
                for (int nt = 0; nt < 2; ++nt)
                    acc2[(gg << 2) + m][nt] = __builtin_amdgcn_mfma_f32_16x16x32_f16(
                        a2[m], bw[nt], acc2[(gg << 2) + m][nt], 0, 0, 0);
        }
    }

    // epilogue 2: silu + j-sum, butterfly across quads, store
    float b2v[2];
    #pragma unroll
    for (int nt = 0; nt < 2; ++nt) b2v[nt] = b2[(w << 5) + (nt << 4) + c];

    float s[2] = {0.f, 0.f};
    #pragma unroll
    for (int nt = 0; nt < 2; ++nt)
        #pragma unroll
        for (int mt = 0; mt < 8; ++mt)
            #pragma unroll
            for (int r = 0; r < 4; ++r)
                s[nt] += fast_silu(acc2[mt][nt][r] + b2v[nt]);

    #pragma unroll
    for (int nt = 0; nt < 2; ++nt) {
        s[nt] += __shfl_xor(s[nt], 16);
        s[nt] += __shfl_xor(s[nt], 32);
    }
    if (q < 2)
        out[((size_t)bi << 8) + (w << 5) + (q << 4) + c] = s[q] * 0.0078125f;
}

// ---------------------------------------------------------------------------
extern "C" void kernel_launch(void* const* d_in, const int* in_sizes, int n_in,
                              void* d_out, int out_size, void* d_ws, size_t ws_size,
                              hipStream_t stream)
{
    const float* node  = (const float*)d_in[0];
    const float* edge  = (const float*)d_in[1];
    const float* graph = (const float*)d_in[2];
    const float* W1    = (const float*)d_in[3];
    const float* b1    = (const float*)d_in[4];
    const float* W2    = (const float*)d_in[5];
    const float* b2    = (const float*)d_in[6];
    float* out = (float*)d_out;

    char* ws = (char*)d_ws;
    unsigned short* W2T = (unsigned short*)ws;              // 131072 B
    unsigned short* WeT = (unsigned short*)(ws + 131072);   //  32768 B
    float* pj   = (float*)(ws + 163840);                    // 2 MB
    float* base = (float*)(ws + 163840 + 2097152);          // 2 MB

    pre_w     <<<256, 256, 0, stream>>>(W1, W2, W2T, WeT);
    pre_pjbase<<<256, 256, 0, stream>>>(node, graph, W1, b1, pj, base);
    fused_msg <<<BSZ * NN, 512, 0, stream>>>(edge, pj, base, W2T, WeT, b2, out);
}

// Round 12
// 107.340 us; speedup vs baseline: 3.5660x; 1.0545x over previous
//
#include <hip/hip_runtime.h>

// Problem constants
#define BSZ 16
#define NN  128
#define HH  256
#define LLG 9
#define FFE 48   // edge feature dim (padded to 64 for MFMA K)

typedef float        f32x4 __attribute__((ext_vector_type(4)));
typedef _Float16     f16x8 __attribute__((ext_vector_type(8)));
typedef unsigned int u32x4 __attribute__((ext_vector_type(4)));

static __device__ __forceinline__ unsigned short f2h_bits(float x) {
    _Float16 h = (_Float16)x;   // RNE
    return __builtin_bit_cast(unsigned short, h);
}

static __device__ __forceinline__ float fast_silu(float x) {
    float e = __builtin_amdgcn_exp2f(x * -1.44269504088896341f);
    return x * __builtin_amdgcn_rcpf(1.0f + e);
}

// ---------------------------------------------------------------------------
// Kernel 1: weight transpose + f32->f16 convert.  (proven)
//   WeT[h][f]  (256 x 64, f>=48 zero-padded)  from W1 rows 521..568
//   W2T[ho][k] (256 x 256)                    from W2[k][ho]
// ---------------------------------------------------------------------------
__global__ __launch_bounds__(256) void pre_w(
    const float* __restrict__ W1, const float* __restrict__ W2,
    unsigned short* __restrict__ W2T, unsigned short* __restrict__ WeT)
{
    int tid = blockIdx.x * 256 + threadIdx.x;   // grid 256 -> 65536 threads
    {
        int ho = tid >> 8, k = tid & 255;
        W2T[(ho << 8) + k] = f2h_bits(W2[(k << 8) + ho]);  // coalesced write
    }
    if (tid < 256 * 64) {
        int h = tid >> 6, f = tid & 63;
        WeT[(h << 6) + f] = (f < FFE) ? f2h_bits(W1[(521 + f) * HH + h])
                                      : (unsigned short)0;
    }
}

// ---------------------------------------------------------------------------
// Kernel 2: pj/base precompute — 512-block / 4-rows version (proven fastest:
// R11's 256-block variant was 1 block/CU -> latency-bound, +5.5 us total).
// ---------------------------------------------------------------------------
__global__ __launch_bounds__(256) void pre_pjbase(
    const float* __restrict__ node, const float* __restrict__ graph,
    const float* __restrict__ W1, const float* __restrict__ b1,
    float* __restrict__ pj, float* __restrict__ base)
{
    __shared__ float nrow[4][HH];
    __shared__ float gsh[LLG];
    const int blk = blockIdx.x;
    const int b = blk >> 5;             // 32 row-groups of 4 per batch
    const int r0 = (blk & 31) << 2;
    const int h = threadIdx.x;

    for (int t = h; t < 4 * HH; t += 256) {
        int r = t >> 8, k = t & 255;
        nrow[r][k] = node[(((size_t)b * NN) + r0 + r) * HH + k];
    }
    if (h < LLG) gsh[h] = graph[b * LLG + h];
    __syncthreads();

    float accj[4] = {0,0,0,0};
    float acci[4] = {0,0,0,0};
    for (int k = 0; k < HH; ++k) {
        float wj = W1[k * HH + h];
        float wi = W1[(k + HH) * HH + h];
        #pragma unroll
        for (int r = 0; r < 4; ++r) {
            float nv = nrow[r][k];
            accj[r] = fmaf(nv, wj, accj[r]);
            acci[r] = fmaf(nv, wi, acci[r]);
        }
    }
    float accg = b1[h];
    #pragma unroll
    for (int l = 0; l < LLG; ++l)
        accg = fmaf(gsh[l], W1[(2 * HH + l) * HH + h], accg);

    #pragma unroll
    for (int r = 0; r < 4; ++r) {
        size_t off = (((size_t)b * NN) + r0 + r) * HH + h;
        pj[off]   = accj[r];
        base[off] = acci[r] + accg;
    }
}

// ---------------------------------------------------------------------------
// Kernel 3: fused main — round-5 structure VERBATIM (best: 92 us) + T1
// XCD-chunked block swizzle (keeps pj/base working set XCD-local; FETCH
// 34.5 -> 27.3 MB measured, dur-neutral but free).
// ---------------------------------------------------------------------------
__global__ __launch_bounds__(512, 4) void fused_msg(
    const float* __restrict__ edge, const float* __restrict__ pj,
    const float* __restrict__ base, const unsigned short* __restrict__ W2T,
    const unsigned short* __restrict__ WeT, const float* __restrict__ b2,
    float* __restrict__ out)
{
    __shared__ unsigned char h1s[NN * HH * 2];   // 64 KB: h1[j][h] f16, swizzled
    __shared__ unsigned char efs[NN * 64 * 2];   // 16 KB: edge[j][f] f16, padded+swizzled
    const int tid  = threadIdx.x;
    const int w    = tid >> 6;         // wave 0..7
    const int lane = tid & 63;
    const int q    = lane >> 4;        // quad 0..3
    const int c    = lane & 15;
    // T1: XCD-chunked swizzle (2048 blocks, 8 XCDs, 2048%8==0 -> bijective)
    const int g    = blockIdx.x;
    const int bi   = ((g & 7) << 8) + (g >> 3);   // b*128 + i
    const int b    = bi >> 7;

    const float* eb = edge + (size_t)bi * (NN * FFE);

    // ---- stage edge block -> f16 LDS, row-padded to 64 f16, XOR-swizzled ----
    #pragma unroll
    for (int p = 0; p < 3; ++p) {
        const int e4 = p * 512 + tid;            // float4 index, < 1536
        const int j  = e4 / 12;                  // 12 float4 per 48-float row
        const int f4 = e4 - j * 12;              // 0..11
        const f32x4 x = *reinterpret_cast<const f32x4*>(eb + (e4 << 2));
        unsigned int lo = __builtin_bit_cast(unsigned int,
                            __builtin_amdgcn_cvt_pkrtz(x[0], x[1]));
        unsigned int hi = __builtin_bit_cast(unsigned int,
                            __builtin_amdgcn_cvt_pkrtz(x[2], x[3]));
        const unsigned int off = (unsigned)(j << 7) +
            (((unsigned)(f4 << 3)) ^ ((unsigned)(j & 7) << 4));
        *reinterpret_cast<uint2*>(&efs[off]) = make_uint2(lo, hi);
    }
    {   // zero-fill padded f in [48,64)
        const int j = tid >> 2, gg = tid & 3;
        const unsigned int off = (unsigned)(j << 7) +
            (((unsigned)(96 + (gg << 3))) ^ ((unsigned)(j & 7) << 4));
        *reinterpret_cast<uint2*>(&efs[off]) = make_uint2(0u, 0u);
    }
    __syncthreads();

    // ------------------ GEMM1: D1[h(32), j(128)] ------------------
    f32x4 acc1[2][8];
    #pragma unroll
    for (int mt = 0; mt < 2; ++mt)
        #pragma unroll
        for (int nt = 0; nt < 8; ++nt) acc1[mt][nt] = f32x4{0.f, 0.f, 0.f, 0.f};

    #pragma unroll
    for (int kk = 0; kk < 2; ++kk) {
        const int koff = (kk << 5) + (q << 3);   // f16-units f offset
        const int fb   = koff << 1;              // byte offset in efs row
        f16x8 af[2];
        #pragma unroll
        for (int mt = 0; mt < 2; ++mt) {
            const int row = (w << 5) + (mt << 4) + c;       // h
            af[mt] = *reinterpret_cast<const f16x8*>(WeT + (row << 6) + koff);
        }
        #pragma unroll
        for (int nt = 0; nt < 8; ++nt) {
            const int j = (nt << 4) + c;
            const f16x8 bf = *reinterpret_cast<const f16x8*>(
                &efs[(unsigned)(j << 7) +
                     (((unsigned)fb) ^ ((unsigned)(j & 7) << 4))]);
            #pragma unroll
            for (int mt = 0; mt < 2; ++mt)
                acc1[mt][nt] = __builtin_amdgcn_mfma_f32_16x16x32_f16(
                    af[mt], bf, acc1[mt][nt], 0, 0, 0);
        }
    }

    // epilogue 1: z1 -> silu -> f16 -> h1s (swizzle: byte ^= (j&7)<<4)
    #pragma unroll
    for (int mt = 0; mt < 2; ++mt) {
        const int h0 = (w << 5) + (mt << 4) + (q << 2);
        const f32x4 bb = *reinterpret_cast<const f32x4*>(
            base + ((size_t)bi << 8) + h0);
        #pragma unroll
        for (int nt = 0; nt < 8; ++nt) {
            const int jc = (nt << 4) + c;
            const f32x4 pjv = *reinterpret_cast<const f32x4*>(
                pj + (((size_t)b << 7) + jc) * HH + h0);
            float s0 = fast_silu(acc1[mt][nt][0] + bb[0] + pjv[0]);
            float s1 = fast_silu(acc1[mt][nt][1] + bb[1] + pjv[1]);
            float s2 = fast_silu(acc1[mt][nt][2] + bb[2] + pjv[2]);
            float s3 = fast_silu(acc1[mt][nt][3] + bb[3] + pjv[3]);
            unsigned int lo = __builtin_bit_cast(unsigned int,
                                __builtin_amdgcn_cvt_pkrtz(s0, s1));
            unsigned int hi = __builtin_bit_cast(unsigned int,
                                __builtin_amdgcn_cvt_pkrtz(s2, s3));
            const unsigned int off = (unsigned)(jc << 9) +
                (((unsigned)(h0 << 1)) ^ ((unsigned)(jc & 7) << 4));
            *reinterpret_cast<uint2*>(&h1s[off]) = make_uint2(lo, hi);
        }
    }
    __syncthreads();

    // ------------------ GEMM2: D2[jc(128), ho(32)] ------------------
    f32x4 acc2[8][2];
    #pragma unroll
    for (int mt = 0; mt < 8; ++mt)
        #pragma unroll
        for (int nt = 0; nt < 2; ++nt) acc2[mt][nt] = f32x4{0.f, 0.f, 0.f, 0.f};

    #pragma unroll 2
    for (int kk = 0; kk < 8; ++kk) {
        const int kb = (kk << 6) + (q << 4);     // byte offset of k-slice
        f16x8 bw[2];
        #pragma unroll
        for (int nt = 0; nt < 2; ++nt) {
            const int ho = (w << 5) + (nt << 4) + c;
            bw[nt] = *reinterpret_cast<const f16x8*>(
                W2T + (ho << 8) + (kk << 5) + (q << 3));
        }
        #pragma unroll
        for (int gg = 0; gg < 2; ++gg) {
            f16x8 a2[4];
            #pragma unroll
            for (int m = 0; m < 4; ++m) {
                const int jc = ((gg << 2) + m) * 16 + c;
                const unsigned int off = (unsigned)(jc << 9) +
                    (((unsigned)kb) ^ ((unsigned)(jc & 7) << 4));
                a2[m] = *reinterpret_cast<const f16x8*>(&h1s[off]);
            }
            #pragma unroll
            for (int m = 0; m < 4; ++m)
                #pragma unroll
                for (int nt = 0; nt < 2; ++nt)
                    acc2[(gg << 2) + m][nt] = __builtin_amdgcn_mfma_f32_16x16x32_f16(
                        a2[m], bw[nt], acc2[(gg << 2) + m][nt], 0, 0, 0);
        }
    }

    // epilogue 2: silu + j-sum, butterfly across quads, store
    float b2v[2];
    #pragma unroll
    for (int nt = 0; nt < 2; ++nt) b2v[nt] = b2[(w << 5) + (nt << 4) + c];

    float s[2] = {0.f, 0.f};
    #pragma unroll
    for (int nt = 0; nt < 2; ++nt)
        #pragma unroll
        for (int mt = 0; mt < 8; ++mt)
            #pragma unroll
            for (int r = 0; r < 4; ++r)
                s[nt] += fast_silu(acc2[mt][nt][r] + b2v[nt]);

    #pragma unroll
    for (int nt = 0; nt < 2; ++nt) {
        s[nt] += __shfl_xor(s[nt], 16);
        s[nt] += __shfl_xor(s[nt], 32);
    }
    if (q < 2)
        out[((size_t)bi << 8) + (w << 5) + (q << 4) + c] = s[q] * 0.0078125f;
}

// ---------------------------------------------------------------------------
extern "C" void kernel_launch(void* const* d_in, const int* in_sizes, int n_in,
                              void* d_out, int out_size, void* d_ws, size_t ws_size,
                              hipStream_t stream)
{
    const float* node  = (const float*)d_in[0];
    const float* edge  = (const float*)d_in[1];
    const float* graph = (const float*)d_in[2];
    const float* W1    = (const float*)d_in[3];
    const float* b1    = (const float*)d_in[4];
    const float* W2    = (const float*)d_in[5];
    const float* b2    = (const float*)d_in[6];
    float* out = (float*)d_out;

    char* ws = (char*)d_ws;
    unsigned short* W2T = (unsigned short*)ws;              // 131072 B
    unsigned short* WeT = (unsigned short*)(ws + 131072);   //  32768 B
    float* pj   = (float*)(ws + 163840);                    // 2 MB
    float* base = (float*)(ws + 163840 + 2097152);          // 2 MB

    pre_w     <<<256, 256, 0, stream>>>(W1, W2, W2T, WeT);
    pre_pjbase<<<512, 256, 0, stream>>>(node, graph, W1, b1, pj, base);
    fused_msg <<<BSZ * NN, 512, 0, stream>>>(edge, pj, base, W2T, WeT, b2, out);
}